// Round 7
// baseline (456.562 us; speedup 1.0000x reference)
//
#include <hip/hip_runtime.h>
#include <hip/hip_bf16.h>
#include <math.h>

#define NH 16
#define NOPE 128
#define ROPE 64
#define VDIM 128
#define HD 192          // HEAD_DIM
#define SEQ 2048
#define DIM 2048
#define QKD (NH * HD)   // 3072
#define VD  (NH * VDIM) // 2048
#define QKVS 8192       // fused q|k|v row stride (shorts): [q 3072][k 3072][v 2048]

typedef __attribute__((ext_vector_type(8))) short short8;   // 8 bf16 = 4 VGPRs
typedef __attribute__((ext_vector_type(4))) short short4v;
typedef __attribute__((ext_vector_type(4))) float f32x4;
typedef unsigned int u32;

static __device__ inline short f2bf(float f) {
  union { float f; unsigned u; } v; v.f = f;
  unsigned r = (v.u + 0x7fffu + ((v.u >> 16) & 1u)) >> 16;
  return (short)r;
}
static __device__ inline float bf2f(unsigned short u) {
  union { unsigned u; float f; } v; v.u = ((unsigned)u) << 16;
  return v.f;
}

// async global->LDS, 16B/lane. LDS dest = wave-uniform base + lane*16.
static __device__ __forceinline__ void gload16(const short* g, short* l) {
  __builtin_amdgcn_global_load_lds(
      (const __attribute__((address_space(1))) u32*)g,
      (__attribute__((address_space(3))) u32*)l, 16, 0, 0);
}

// ---------------------------------------------------------------------------
// bf16 MFMA GEMM (m97): C = A[M][K]@B[N][K]^T with leading-dim params.
// ---------------------------------------------------------------------------
template <bool BF16OUT>
__global__ __launch_bounds__(256) void gemm_bt(
    const short* __restrict__ A, const short* __restrict__ B,
    void* __restrict__ Cv, int K, int lda, int ldb, int ldc, float oscale) {
  __shared__ __align__(16) short As[128 * 32];
  __shared__ __align__(16) short Bs[128 * 32];

  const int tid = threadIdx.x;
  const int lane = tid & 63;
  const int wave = tid >> 6;
  const int wr = wave >> 1, wc = wave & 1;
  const int lane15 = lane & 15, quad = lane >> 4;
  const int m0 = blockIdx.y * 128, n0 = blockIdx.x * 128;
  const int sr = tid >> 2;
  const int sc = (tid & 3) * 8;

  f32x4 acc[4][4];
#pragma unroll
  for (int i = 0; i < 4; ++i)
#pragma unroll
    for (int j = 0; j < 4; ++j) acc[i][j] = (f32x4)(0.f);

  for (int k0 = 0; k0 < K; k0 += 32) {
    gload16(A + (size_t)(m0 + sr) * lda + k0 + sc, As + tid * 8);
    gload16(A + (size_t)(m0 + sr + 64) * lda + k0 + sc, As + 2048 + tid * 8);
    gload16(B + (size_t)(n0 + sr) * ldb + k0 + sc, Bs + tid * 8);
    gload16(B + (size_t)(n0 + sr + 64) * ldb + k0 + sc, Bs + 2048 + tid * 8);
    __syncthreads();

    short8 af[4], bfr[4];
#pragma unroll
    for (int i = 0; i < 4; ++i)
      af[i] = *(const short8*)&As[(wr * 64 + i * 16 + lane15) * 32 + quad * 8];
#pragma unroll
    for (int j = 0; j < 4; ++j)
      bfr[j] = *(const short8*)&Bs[(wc * 64 + j * 16 + lane15) * 32 + quad * 8];
#pragma unroll
    for (int i = 0; i < 4; ++i)
#pragma unroll
      for (int j = 0; j < 4; ++j)
        acc[i][j] = __builtin_amdgcn_mfma_f32_16x16x32_bf16(af[i], bfr[j], acc[i][j], 0, 0, 0);
    __syncthreads();
  }

#pragma unroll
  for (int i = 0; i < 4; ++i)
#pragma unroll
    for (int j = 0; j < 4; ++j)
#pragma unroll
      for (int r = 0; r < 4; ++r) {
        size_t idx = (size_t)(m0 + wr * 64 + i * 16 + quad * 4 + r) * ldc +
                     n0 + wc * 64 + j * 16 + lane15;
        if (BF16OUT)
          ((short*)Cv)[idx] = f2bf(acc[i][j][r] * oscale);
        else
          ((float*)Cv)[idx] = acc[i][j][r];
      }
}

// ---------------------------------------------------------------------------
// RoPE in-place on fused qkv bf16 [SEQ][QKVS]: q pair + k pair per thread.
// ---------------------------------------------------------------------------
__global__ __launch_bounds__(256) void rope_qk(
    short* __restrict__ qk, const float* __restrict__ cosf, const float* __restrict__ sinf) {
  int idx = blockIdx.x * blockDim.x + threadIdx.x;
  int j = idx & 31;
  int h = (idx >> 5) & (NH - 1);
  int s = idx >> 9;
  if (s >= SEQ) return;

  float c = cosf[s * 32 + j];
  float sn = sinf[s * 32 + j];
  size_t rowb = (size_t)s * QKVS + h * HD + NOPE + 2 * j;

  u32* pq = (u32*)(qk + rowb);
  u32 w = *pq;
  float a = bf2f((unsigned short)(w & 0xffff));
  float b = bf2f((unsigned short)(w >> 16));
  *pq = (u32)(unsigned short)f2bf(a * c - b * sn) |
        ((u32)(unsigned short)f2bf(a * sn + b * c) << 16);

  u32* pk = (u32*)(qk + rowb + QKD);
  w = *pk;
  a = bf2f((unsigned short)(w & 0xffff));
  b = bf2f((unsigned short)(w >> 16));
  *pk = (u32)(unsigned short)f2bf(a * c - b * sn) |
        ((u32)(unsigned short)f2bf(a * sn + b * c) << 16);
}

// ---------------------------------------------------------------------------
// Converts.
// ---------------------------------------------------------------------------
__global__ __launch_bounds__(256) void bf16_convert(
    const float* __restrict__ in, short* __restrict__ out, int n4) {
  int i = blockIdx.x * 256 + threadIdx.x;
  if (i >= n4) return;
  float4 f = ((const float4*)in)[i];
  short4v o;
  o.x = f2bf(f.x); o.y = f2bf(f.y); o.z = f2bf(f.z); o.w = f2bf(f.w);
  ((short4v*)out)[i] = o;
}

// wq|wk|wv -> wqkv bf16 [8192][2048]
__global__ __launch_bounds__(256) void conv_wqkv(
    const float* __restrict__ wq, const float* __restrict__ wk,
    const float* __restrict__ wv, short* __restrict__ wqkv, int n4) {
  int i = blockIdx.x * 256 + threadIdx.x;
  if (i >= n4) return;
  int row = i >> 9;  // 512 float4 per 2048-col row
  float4 f;
  if (row < QKD) f = ((const float4*)wq)[i];
  else if (row < 2 * QKD) f = ((const float4*)wk)[i - QKD * (DIM / 4)];
  else f = ((const float4*)wv)[i - 2 * QKD * (DIM / 4)];
  short4v o;
  o.x = f2bf(f.x); o.y = f2bf(f.y); o.z = f2bf(f.z); o.w = f2bf(f.w);
  ((short4v*)wqkv)[i] = o;
}

// ---------------------------------------------------------------------------
// v bf16 (cols 6144.. of qkv, stride QKVS) -> vtb bf16 [h][d][t] transpose.
// ---------------------------------------------------------------------------
__global__ __launch_bounds__(256) void vt_bf16(
    const short* __restrict__ vb, short* __restrict__ vtb) {
  __shared__ short tile[64][74];
  const int t0 = blockIdx.x * 64;
  const int c0 = blockIdx.y * 64;
  const int tid = threadIdx.x;
#pragma unroll
  for (int i = 0; i < 16; ++i) {
    int idx = i * 256 + tid;
    int r = idx >> 6, c = idx & 63;
    tile[r][c] = vb[(size_t)(t0 + r) * QKVS + c0 + c];
  }
  __syncthreads();
  const int h = c0 >> 7;
  const int dbase = c0 & 127;
#pragma unroll
  for (int i = 0; i < 16; ++i) {
    int idx = i * 256 + tid;
    int d = idx >> 6, t = idx & 63;
    vtb[(size_t)h * VDIM * SEQ + (size_t)(dbase + d) * SEQ + t0 + t] = tile[t][d];
  }
}

// ---------------------------------------------------------------------------
// Split-T flash attention, 2x2 wave layout (wave = 32 q-rows x 32 T-cols).
// Fixed-max softmax => O/l partials additive (cross-wave + cross-chunk).
// ---------------------------------------------------------------------------
#define BQ 64
#define BT 64
#define CHT 8
#define PSTR 36
#define REDSTR 132
#define MFIX 8.0f

__global__ __launch_bounds__(256) void attn_part(
    const short* __restrict__ qk,   // [SEQ][QKVS] bf16
    const short* __restrict__ vtb,  // [NH][VDIM][SEQ] bf16
    short* __restrict__ Opart,      // [1280][64][128] bf16
    float* __restrict__ lpart)      // [1280][64] fp32
{
  __shared__ __align__(16) char smem[50176];
  short* Ks = (short*)smem;                    // 64 x 192 = 24576 B
  short* Vt = (short*)(smem + 24576);          // 128 x 64 = 16384 B
  short* Ps = (short*)(smem + 40960);          // 4 waves x 32 x 36 x 2 = 9216 B
  float* redbuf = (float*)smem;                // epilogue: 64 x 132 dw = 33792 B
  float* lsbuf  = (float*)(smem + 33792);      // 64 fp32

  const int qt = blockIdx.x;
  const int h = blockIdx.y;
  const int chk = blockIdx.z;
  if (chk * CHT > qt) return;

  const int tid = threadIdx.x;
  const int wave = tid >> 6;
  const int wq2 = wave >> 1;      // q-half (32 rows)
  const int wt2 = wave & 1;       // T-half (32 cols)
  const int lane = tid & 63;
  const int lane15 = lane & 15;
  const int quad = lane >> 4;
  const int bb = qt >> 3;
  const int slot = h * 80 + qt + 4 * bb * (bb - 1) + (qt - 8 * bb) * bb + chk;
  const int R0 = qt * BQ;
  const int kt_beg = chk * CHT;
  const int kt_end = min(kt_beg + CHT, qt + 1);
  const float scale = 0.072168784f;  // 1/sqrt(192)

  // Q A-frags: 2 q-chunks x 6 kc
  short8 qf[2][6];
#pragma unroll
  for (int qi = 0; qi < 2; ++qi) {
    const short* qbase =
        qk + (size_t)(R0 + wq2 * 32 + qi * 16 + lane15) * QKVS + h * HD + quad * 8;
#pragma unroll
    for (int kc = 0; kc < 6; ++kc) qf[qi][kc] = *(const short8*)(qbase + kc * 32);
  }

  // staging descriptors (XOR-swizzled)
  const short* kb = qk + QKD;
  const short* gK[6]; short* lK[6];
#pragma unroll
  for (int i = 0; i < 6; ++i) {
    int id = i * 256 + tid;
    int row = id / 24, cX = id - row * 24;
    int ch = cX ^ (row & 7);
    lK[i] = &Ks[id * 8];
    gK[i] = kb + (size_t)row * QKVS + h * HD + ch * 8;
  }
  const short* gV[4]; short* lV[4];
#pragma unroll
  for (int i = 0; i < 4; ++i) {
    int id = i * 256 + tid;
    int row = id >> 3, cX = id & 7;
    int ch = cX ^ (row & 7);
    lV[i] = &Vt[id * 8];
    gV[i] = vtb + (size_t)h * VDIM * SEQ + (size_t)row * SEQ + ch * 8;
  }

  f32x4 oacc[2][8];
#pragma unroll
  for (int qi = 0; qi < 2; ++qi)
#pragma unroll
    for (int ch = 0; ch < 8; ++ch) oacc[qi][ch] = (f32x4)(0.f);
  float lsum[2][4] = {};

  short* pw = &Ps[wave * 32 * PSTR];

  for (int kt = kt_beg; kt < kt_end; ++kt) {
    const int t0 = kt * BT;
    __syncthreads();
#pragma unroll
    for (int i = 0; i < 6; ++i) gload16(gK[i] + (size_t)t0 * QKVS, lK[i]);
#pragma unroll
    for (int i = 0; i < 4; ++i) gload16(gV[i] + t0, lV[i]);
    __syncthreads();

    // S = Q K^T over wave's 32q x 32t
    f32x4 sacc[2][2];
#pragma unroll
    for (int ci = 0; ci < 2; ++ci) {
      const int c = wt2 * 2 + ci;
      const int row = c * 16 + lane15;
#pragma unroll
      for (int qi = 0; qi < 2; ++qi) sacc[qi][ci] = (f32x4)(0.f);
#pragma unroll
      for (int kc = 0; kc < 6; ++kc) {
        int cX = (4 * kc + quad) ^ (lane15 & 7);
        short8 kf = *(const short8*)&Ks[row * 192 + cX * 8];
#pragma unroll
        for (int qi = 0; qi < 2; ++qi)
          sacc[qi][ci] = __builtin_amdgcn_mfma_f32_16x16x32_bf16(qf[qi][kc], kf, sacc[qi][ci], 0, 0, 0);
      }
    }

    if (kt == qt) {  // diagonal tile mask (local coords)
#pragma unroll
      for (int qi = 0; qi < 2; ++qi)
#pragma unroll
        for (int ci = 0; ci < 2; ++ci)
#pragma unroll
          for (int r = 0; r < 4; ++r) {
            int tloc = (wt2 * 2 + ci) * 16 + lane15;
            int qloc = wq2 * 32 + qi * 16 + quad * 4 + r;
            if (tloc > qloc) sacc[qi][ci][r] = -1e30f;
          }
    }

    // P = exp(S*scale - MFIX); stage to per-wave scratch [32q][32t]
#pragma unroll
    for (int qi = 0; qi < 2; ++qi)
#pragma unroll
      for (int ci = 0; ci < 2; ++ci)
#pragma unroll
        for (int r = 0; r < 4; ++r) {
          float p = __expf(sacc[qi][ci][r] * scale - MFIX);
          lsum[qi][r] += p;
          pw[(qi * 16 + quad * 4 + r) * PSTR + ci * 16 + lane15] = f2bf(p);
        }

    // PV: k=32 over wave's T-half
#pragma unroll
    for (int qi = 0; qi < 2; ++qi) {
      short8 pf = *(const short8*)&pw[(qi * 16 + lane15) * PSTR + quad * 8];
#pragma unroll
      for (int ch = 0; ch < 8; ++ch) {
        int cX = (wt2 * 4 + quad) ^ (lane15 & 7);
        short8 vf = *(const short8*)&Vt[(ch * 16 + lane15) * 64 + cX * 8];
        oacc[qi][ch] = __builtin_amdgcn_mfma_f32_16x16x32_bf16(pf, vf, oacc[qi][ch], 0, 0, 0);
      }
    }
  }

  // ---- epilogue: reduce wt2=1 into wt2=0 via LDS, then store partials ----
  // wave-internal l reduction over lane15 (T within wave)
#pragma unroll
  for (int qi = 0; qi < 2; ++qi)
#pragma unroll
    for (int r = 0; r < 4; ++r) {
      float s = lsum[qi][r];
      s += __shfl_xor(s, 1, 64);
      s += __shfl_xor(s, 2, 64);
      s += __shfl_xor(s, 4, 64);
      s += __shfl_xor(s, 8, 64);
      lsum[qi][r] = s;
    }

  __syncthreads();  // Ks/Vt reads done; redbuf overwrite safe
  if (wt2 == 1) {
#pragma unroll
    for (int qi = 0; qi < 2; ++qi)
#pragma unroll
      for (int ch = 0; ch < 8; ++ch)
#pragma unroll
        for (int r = 0; r < 4; ++r)
          redbuf[(wq2 * 32 + qi * 16 + quad * 4 + r) * REDSTR + ch * 16 + lane15] =
              oacc[qi][ch][r];
    if (lane15 == 0) {
#pragma unroll
      for (int qi = 0; qi < 2; ++qi)
#pragma unroll
        for (int r = 0; r < 4; ++r)
          lsbuf[wq2 * 32 + qi * 16 + quad * 4 + r] = lsum[qi][r];
    }
  }
  __syncthreads();
  if (wt2 == 0) {
    short* op = Opart + (size_t)slot * (64 * 128);
#pragma unroll
    for (int qi = 0; qi < 2; ++qi)
#pragma unroll
      for (int ch = 0; ch < 8; ++ch)
#pragma unroll
        for (int r = 0; r < 4; ++r) {
          int q = wq2 * 32 + qi * 16 + quad * 4 + r;
          op[q * 128 + ch * 16 + lane15] =
              f2bf(oacc[qi][ch][r] + redbuf[q * REDSTR + ch * 16 + lane15]);
        }
    if (lane15 == 0) {
#pragma unroll
      for (int qi = 0; qi < 2; ++qi)
#pragma unroll
        for (int r = 0; r < 4; ++r) {
          int q = wq2 * 32 + qi * 16 + quad * 4 + r;
          lpart[(size_t)slot * 64 + q] = lsum[qi][r] + lsbuf[q];
        }
    }
  }
}

// ---------------------------------------------------------------------------
// Phase B: sum chunk partials, normalize, write aob (into v-cols of qkv).
// ---------------------------------------------------------------------------
__global__ __launch_bounds__(256) void attn_combine(
    const short* __restrict__ Opart, const float* __restrict__ lpart,
    short* __restrict__ aob) {   // aob = qkv + 6144, row stride QKVS
  const int qt = blockIdx.x, h = blockIdx.y;
  const int nact = (qt >> 3) + 1;
  const int bb = qt >> 3;
  const int base = h * 80 + qt + 4 * bb * (bb - 1) + (qt - 8 * bb) * bb;
  const int tid = threadIdx.x;
  const int row = tid >> 2;
  const int cg = (tid & 3) * 32;

  float acc[32];
#pragma unroll
  for (int e = 0; e < 32; ++e) acc[e] = 0.f;
  float lsum = 0.f;

  for (int c = 0; c < nact; ++c) {
    const short* sp = Opart + (size_t)(base + c) * (64 * 128) + row * 128 + cg;
    lsum += lpart[(size_t)(base + c) * 64 + row];
#pragma unroll
    for (int g = 0; g < 4; ++g) {
      short8 vv = *(const short8*)(sp + g * 8);
#pragma unroll
      for (int e = 0; e < 8; ++e) acc[g * 8 + e] += bf2f((unsigned short)vv[e]);
    }
  }

  float inv = 1.f / lsum;
#pragma unroll
  for (int g = 0; g < 4; ++g) {
    short8 ov;
#pragma unroll
    for (int e = 0; e < 8; ++e) ov[e] = f2bf(acc[g * 8 + e] * inv);
    *(short8*)(aob + (size_t)(qt * 64 + row) * QKVS + h * 128 + cg + g * 8) = ov;
  }
}

// ---------------------------------------------------------------------------
// Workspace (bytes), peak 75,497,472 (< proven 79,691,776):
//   [0,        8388608)  xb  -> wo_b (after qkv gemm)
//   [8388608, 41943040)  wqkv -> {vtb@8388608, Opart@16777216, lpart@37748736}
//   [41943040,75497472)  qkv bf16 [2048][8192]; aob lives in v-cols (6144+)
// ---------------------------------------------------------------------------
extern "C" void kernel_launch(void* const* d_in, const int* in_sizes, int n_in,
                              void* d_out, int out_size, void* d_ws, size_t ws_size,
                              hipStream_t stream) {
  const float* x  = (const float*)d_in[0];
  const float* wq = (const float*)d_in[1];
  const float* wk = (const float*)d_in[2];
  const float* wv = (const float*)d_in[3];
  const float* wo = (const float*)d_in[4];
  const float* fc = (const float*)d_in[5];
  const float* fs = (const float*)d_in[6];

  char* ws8 = (char*)d_ws;
  short* xb    = (short*)(ws8 + 0);
  short* wo_b  = (short*)(ws8 + 0);
  short* wqkv  = (short*)(ws8 + 8388608);
  short* vtb   = (short*)(ws8 + 8388608);
  short* Opart = (short*)(ws8 + 16777216);
  float* lpart = (float*)(ws8 + 37748736);
  short* qkv   = (short*)(ws8 + 41943040);
  float* out   = (float*)d_out;

  const int NX4 = DIM * DIM / 4;
  const int NQKV4 = QKVS * DIM / 4;
  const int ROPE_GRID = (SEQ * NH * 32) / 256;

  bf16_convert<<<(NX4 + 255) / 256, 256, 0, stream>>>(x, xb, NX4);
  conv_wqkv<<<(NQKV4 + 255) / 256, 256, 0, stream>>>(wq, wk, wv, wqkv, NQKV4);

  // fused QKV projection: qkv [2048][8192]
  gemm_bt<true><<<dim3(QKVS / 128, SEQ / 128), 256, 0, stream>>>(
      xb, wqkv, qkv, DIM, DIM, DIM, QKVS, 1.0f);
  rope_qk<<<ROPE_GRID, 256, 0, stream>>>(qkv, fc, fs);
  vt_bf16<<<dim3(SEQ / 64, VD / 64), 256, 0, stream>>>(qkv + 2 * QKD, vtb);

  // wo convert (xb dead after qkv gemm)
  bf16_convert<<<(NX4 + 255) / 256, 256, 0, stream>>>(wo, wo_b, NX4);

  // split-T attention
  attn_part<<<dim3(SEQ / BQ, NH, 4), 256, 0, stream>>>(qkv, vtb, Opart, lpart);
  attn_combine<<<dim3(SEQ / BQ, NH), 256, 0, stream>>>(Opart, lpart, qkv + 2 * QKD);

  // output projection (A = aob in v-cols, lda = QKVS)
  gemm_bt<false><<<dim3(DIM / 128, SEQ / 128), 256, 0, stream>>>(
      qkv + 2 * QKD, wo_b, out, DIM, QKVS, DIM, DIM, 1.0f);
}

// Round 8
// 398.423 us; speedup vs baseline: 1.1459x; 1.1459x over previous
//
#include <hip/hip_runtime.h>
#include <hip/hip_bf16.h>
#include <math.h>

#define NH 16
#define NOPE 128
#define ROPE 64
#define VDIM 128
#define HD 192          // HEAD_DIM
#define SEQ 2048
#define DIM 2048
#define QKD (NH * HD)   // 3072
#define VD  (NH * VDIM) // 2048
#define QKVS 8192       // fused q|k|v row stride (shorts): [q 3072][k 3072][v 2048]

typedef __attribute__((ext_vector_type(8))) short short8;   // 8 bf16 = 4 VGPRs
typedef __attribute__((ext_vector_type(4))) short short4v;
typedef __attribute__((ext_vector_type(4))) float f32x4;
typedef unsigned int u32;

static __device__ inline short f2bf(float f) {
  union { float f; unsigned u; } v; v.f = f;
  unsigned r = (v.u + 0x7fffu + ((v.u >> 16) & 1u)) >> 16;
  return (short)r;
}
static __device__ inline float bf2f(unsigned short u) {
  union { unsigned u; float f; } v; v.u = ((unsigned)u) << 16;
  return v.f;
}

// async global->LDS, 16B/lane. LDS dest = wave-uniform base + lane*16.
static __device__ __forceinline__ void gload16(const short* g, short* l) {
  __builtin_amdgcn_global_load_lds(
      (const __attribute__((address_space(1))) u32*)g,
      (__attribute__((address_space(3))) u32*)l, 16, 0, 0);
}

// ---------------------------------------------------------------------------
// bf16 MFMA GEMM (m97): C = A[M][K]@B[N][K]^T with leading-dim params.
// ---------------------------------------------------------------------------
template <bool BF16OUT>
__global__ __launch_bounds__(256) void gemm_bt(
    const short* __restrict__ A, const short* __restrict__ B,
    void* __restrict__ Cv, int K, int lda, int ldb, int ldc, float oscale) {
  __shared__ __align__(16) short As[128 * 32];
  __shared__ __align__(16) short Bs[128 * 32];

  const int tid = threadIdx.x;
  const int lane = tid & 63;
  const int wave = tid >> 6;
  const int wr = wave >> 1, wc = wave & 1;
  const int lane15 = lane & 15, quad = lane >> 4;
  const int m0 = blockIdx.y * 128, n0 = blockIdx.x * 128;
  const int sr = tid >> 2;
  const int sc = (tid & 3) * 8;

  f32x4 acc[4][4];
#pragma unroll
  for (int i = 0; i < 4; ++i)
#pragma unroll
    for (int j = 0; j < 4; ++j) acc[i][j] = (f32x4)(0.f);

  for (int k0 = 0; k0 < K; k0 += 32) {
    gload16(A + (size_t)(m0 + sr) * lda + k0 + sc, As + tid * 8);
    gload16(A + (size_t)(m0 + sr + 64) * lda + k0 + sc, As + 2048 + tid * 8);
    gload16(B + (size_t)(n0 + sr) * ldb + k0 + sc, Bs + tid * 8);
    gload16(B + (size_t)(n0 + sr + 64) * ldb + k0 + sc, Bs + 2048 + tid * 8);
    __syncthreads();

    short8 af[4], bfr[4];
#pragma unroll
    for (int i = 0; i < 4; ++i)
      af[i] = *(const short8*)&As[(wr * 64 + i * 16 + lane15) * 32 + quad * 8];
#pragma unroll
    for (int j = 0; j < 4; ++j)
      bfr[j] = *(const short8*)&Bs[(wc * 64 + j * 16 + lane15) * 32 + quad * 8];
#pragma unroll
    for (int i = 0; i < 4; ++i)
#pragma unroll
      for (int j = 0; j < 4; ++j)
        acc[i][j] = __builtin_amdgcn_mfma_f32_16x16x32_bf16(af[i], bfr[j], acc[i][j], 0, 0, 0);
    __syncthreads();
  }

#pragma unroll
  for (int i = 0; i < 4; ++i)
#pragma unroll
    for (int j = 0; j < 4; ++j)
#pragma unroll
      for (int r = 0; r < 4; ++r) {
        size_t idx = (size_t)(m0 + wr * 64 + i * 16 + quad * 4 + r) * ldc +
                     n0 + wc * 64 + j * 16 + lane15;
        if (BF16OUT)
          ((short*)Cv)[idx] = f2bf(acc[i][j][r] * oscale);
        else
          ((float*)Cv)[idx] = acc[i][j][r];
      }
}

// ---------------------------------------------------------------------------
// RoPE in-place on fused qkv bf16 [SEQ][QKVS]: q pair + k pair per thread.
// ---------------------------------------------------------------------------
__global__ __launch_bounds__(256) void rope_qk(
    short* __restrict__ qk, const float* __restrict__ cosf, const float* __restrict__ sinf) {
  int idx = blockIdx.x * blockDim.x + threadIdx.x;
  int j = idx & 31;
  int h = (idx >> 5) & (NH - 1);
  int s = idx >> 9;
  if (s >= SEQ) return;

  float c = cosf[s * 32 + j];
  float sn = sinf[s * 32 + j];
  size_t rowb = (size_t)s * QKVS + h * HD + NOPE + 2 * j;

  u32* pq = (u32*)(qk + rowb);
  u32 w = *pq;
  float a = bf2f((unsigned short)(w & 0xffff));
  float b = bf2f((unsigned short)(w >> 16));
  *pq = (u32)(unsigned short)f2bf(a * c - b * sn) |
        ((u32)(unsigned short)f2bf(a * sn + b * c) << 16);

  u32* pk = (u32*)(qk + rowb + QKD);
  w = *pk;
  a = bf2f((unsigned short)(w & 0xffff));
  b = bf2f((unsigned short)(w >> 16));
  *pk = (u32)(unsigned short)f2bf(a * c - b * sn) |
        ((u32)(unsigned short)f2bf(a * sn + b * c) << 16);
}

// ---------------------------------------------------------------------------
// Converts.
// ---------------------------------------------------------------------------
__global__ __launch_bounds__(256) void bf16_convert(
    const float* __restrict__ in, short* __restrict__ out, int n4) {
  int i = blockIdx.x * 256 + threadIdx.x;
  if (i >= n4) return;
  float4 f = ((const float4*)in)[i];
  short4v o;
  o.x = f2bf(f.x); o.y = f2bf(f.y); o.z = f2bf(f.z); o.w = f2bf(f.w);
  ((short4v*)out)[i] = o;
}

// wq|wk|wv -> wqkv bf16 [8192][2048]
__global__ __launch_bounds__(256) void conv_wqkv(
    const float* __restrict__ wq, const float* __restrict__ wk,
    const float* __restrict__ wv, short* __restrict__ wqkv, int n4) {
  int i = blockIdx.x * 256 + threadIdx.x;
  if (i >= n4) return;
  int row = i >> 9;  // 512 float4 per 2048-col row
  float4 f;
  if (row < QKD) f = ((const float4*)wq)[i];
  else if (row < 2 * QKD) f = ((const float4*)wk)[i - QKD * (DIM / 4)];
  else f = ((const float4*)wv)[i - 2 * QKD * (DIM / 4)];
  short4v o;
  o.x = f2bf(f.x); o.y = f2bf(f.y); o.z = f2bf(f.z); o.w = f2bf(f.w);
  ((short4v*)wqkv)[i] = o;
}

// ---------------------------------------------------------------------------
// v bf16 (cols 6144.. of qkv, stride QKVS) -> vtb bf16 [h][d][t] transpose.
// ---------------------------------------------------------------------------
__global__ __launch_bounds__(256) void vt_bf16(
    const short* __restrict__ vb, short* __restrict__ vtb) {
  __shared__ short tile[64][74];
  const int t0 = blockIdx.x * 64;
  const int c0 = blockIdx.y * 64;
  const int tid = threadIdx.x;
#pragma unroll
  for (int i = 0; i < 16; ++i) {
    int idx = i * 256 + tid;
    int r = idx >> 6, c = idx & 63;
    tile[r][c] = vb[(size_t)(t0 + r) * QKVS + c0 + c];
  }
  __syncthreads();
  const int h = c0 >> 7;
  const int dbase = c0 & 127;
#pragma unroll
  for (int i = 0; i < 16; ++i) {
    int idx = i * 256 + tid;
    int d = idx >> 6, t = idx & 63;
    vtb[(size_t)h * VDIM * SEQ + (size_t)(dbase + d) * SEQ + t0 + t] = tile[t][d];
  }
}

// ---------------------------------------------------------------------------
// Split-T flash attention (R6 1x4 wave layout: wave = 16 q-rows x 64 T-cols).
// 76 VGPR -> 4 waves/SIMD; occupancy is what wins here (R7 post-mortem).
// Fixed-max softmax => partials additive across chunks.
// ---------------------------------------------------------------------------
#define BQ 64
#define BT 64
#define CHT 8
#define PSTR 76
#define MFIX 8.0f

__global__ __launch_bounds__(256) void attn_part(
    const short* __restrict__ qk,   // [SEQ][QKVS] bf16
    const short* __restrict__ vtb,  // [NH][VDIM][SEQ] bf16
    short* __restrict__ Opart,      // [1280][64][128] bf16
    float* __restrict__ lpart)      // [1280][64] fp32
{
  __shared__ __align__(16) short Ks[BT * 192];    // 24576 B
  __shared__ __align__(16) short Vt[VDIM * 64];   // 16384 B
  __shared__ __align__(16) short Ps[4 * 16 * PSTR];

  const int qt = blockIdx.x;
  const int h = blockIdx.y;
  const int chk = blockIdx.z;
  if (chk * CHT > qt) return;

  const int tid = threadIdx.x;
  const int wave = tid >> 6;
  const int lane = tid & 63;
  const int lane15 = lane & 15;
  const int quad = lane >> 4;
  const int bb = qt >> 3;
  const int slot = h * 80 + qt + 4 * bb * (bb - 1) + (qt - 8 * bb) * bb + chk;
  const int R0 = qt * BQ;
  const int kt_beg = chk * CHT;
  const int kt_end = min(kt_beg + CHT, qt + 1);
  const float scale = 0.072168784f;  // 1/sqrt(192)

  // Q A-frags
  const int qrow = R0 + wave * 16 + lane15;
  short8 qf[6];
  const short* qbase = qk + (size_t)qrow * QKVS + h * HD + quad * 8;
#pragma unroll
  for (int kc = 0; kc < 6; ++kc) qf[kc] = *(const short8*)(qbase + kc * 32);

  // staging descriptors (XOR-swizzled)
  const short* kb = qk + QKD;
  const short* gK[6]; short* lK[6];
#pragma unroll
  for (int i = 0; i < 6; ++i) {
    int id = i * 256 + tid;
    int row = id / 24, cX = id - row * 24;
    int ch = cX ^ (row & 7);
    lK[i] = &Ks[id * 8];
    gK[i] = kb + (size_t)row * QKVS + h * HD + ch * 8;
  }
  const short* gV[4]; short* lV[4];
#pragma unroll
  for (int i = 0; i < 4; ++i) {
    int id = i * 256 + tid;
    int row = id >> 3, cX = id & 7;
    int ch = cX ^ (row & 7);
    lV[i] = &Vt[id * 8];
    gV[i] = vtb + (size_t)h * VDIM * SEQ + (size_t)row * SEQ + ch * 8;
  }

  f32x4 oacc[8];
#pragma unroll
  for (int i = 0; i < 8; ++i) oacc[i] = (f32x4)(0.f);
  float lsum[4] = {0.f, 0.f, 0.f, 0.f};

  short* pw = &Ps[wave * 16 * PSTR];

  for (int kt = kt_beg; kt < kt_end; ++kt) {
    const int t0 = kt * BT;
    __syncthreads();
#pragma unroll
    for (int i = 0; i < 6; ++i) gload16(gK[i] + (size_t)t0 * QKVS, lK[i]);
#pragma unroll
    for (int i = 0; i < 4; ++i) gload16(gV[i] + t0, lV[i]);
    __syncthreads();

    // S = Q K^T
    f32x4 sacc[4];
#pragma unroll
    for (int c = 0; c < 4; ++c) {
      sacc[c] = (f32x4)(0.f);
      const int row = c * 16 + lane15;
#pragma unroll
      for (int kc = 0; kc < 6; ++kc) {
        int cX = (4 * kc + quad) ^ (lane15 & 7);
        short8 kf = *(const short8*)&Ks[row * 192 + cX * 8];
        sacc[c] = __builtin_amdgcn_mfma_f32_16x16x32_bf16(qf[kc], kf, sacc[c], 0, 0, 0);
      }
    }

    if (kt == qt) {  // diagonal tile mask
#pragma unroll
      for (int c = 0; c < 4; ++c)
#pragma unroll
        for (int r = 0; r < 4; ++r) {
          int tloc = c * 16 + lane15;
          int qloc = wave * 16 + quad * 4 + r;
          if (tloc > qloc) sacc[c][r] = -1e30f;
        }
    }

    // P = exp(S*scale - MFIX); partial row sums; stage P bf16
#pragma unroll
    for (int c = 0; c < 4; ++c)
#pragma unroll
      for (int r = 0; r < 4; ++r) {
        float p = __expf(sacc[c][r] * scale - MFIX);
        lsum[r] += p;
        pw[(quad * 4 + r) * PSTR + c * 16 + lane15] = f2bf(p);
      }

    short8 pf0 = *(const short8*)&pw[lane15 * PSTR + quad * 8];
    short8 pf1 = *(const short8*)&pw[lane15 * PSTR + 32 + quad * 8];
#pragma unroll
    for (int ch = 0; ch < 8; ++ch) {
      const int row = ch * 16 + lane15;
      int cX0 = quad ^ (lane15 & 7);
      int cX1 = (4 + quad) ^ (lane15 & 7);
      short8 vf0 = *(const short8*)&Vt[row * 64 + cX0 * 8];
      short8 vf1 = *(const short8*)&Vt[row * 64 + cX1 * 8];
      oacc[ch] = __builtin_amdgcn_mfma_f32_16x16x32_bf16(pf0, vf0, oacc[ch], 0, 0, 0);
      oacc[ch] = __builtin_amdgcn_mfma_f32_16x16x32_bf16(pf1, vf1, oacc[ch], 0, 0, 0);
    }
  }

  // epilogue: write unnormalized partials
  short* op = Opart + (size_t)slot * (64 * 128);
#pragma unroll
  for (int ch = 0; ch < 8; ++ch)
#pragma unroll
    for (int r = 0; r < 4; ++r)
      op[(wave * 16 + quad * 4 + r) * 128 + ch * 16 + lane15] = f2bf(oacc[ch][r]);

  float red[4];
#pragma unroll
  for (int r = 0; r < 4; ++r) {
    float s = lsum[r];
    s += __shfl_xor(s, 1, 64);
    s += __shfl_xor(s, 2, 64);
    s += __shfl_xor(s, 4, 64);
    s += __shfl_xor(s, 8, 64);
    red[r] = s;
  }
  if (lane15 == 0) {
#pragma unroll
    for (int r = 0; r < 4; ++r)
      lpart[(size_t)slot * 64 + wave * 16 + quad * 4 + r] = red[r];
  }
}

// ---------------------------------------------------------------------------
// Phase B: sum chunk partials, normalize, write aob (into v-cols of qkv).
// ---------------------------------------------------------------------------
__global__ __launch_bounds__(256) void attn_combine(
    const short* __restrict__ Opart, const float* __restrict__ lpart,
    short* __restrict__ aob) {   // aob = qkv + 6144, row stride QKVS
  const int qt = blockIdx.x, h = blockIdx.y;
  const int nact = (qt >> 3) + 1;
  const int bb = qt >> 3;
  const int base = h * 80 + qt + 4 * bb * (bb - 1) + (qt - 8 * bb) * bb;
  const int tid = threadIdx.x;
  const int row = tid >> 2;
  const int cg = (tid & 3) * 32;

  float acc[32];
#pragma unroll
  for (int e = 0; e < 32; ++e) acc[e] = 0.f;
  float lsum = 0.f;

  for (int c = 0; c < nact; ++c) {
    const short* sp = Opart + (size_t)(base + c) * (64 * 128) + row * 128 + cg;
    lsum += lpart[(size_t)(base + c) * 64 + row];
#pragma unroll
    for (int g = 0; g < 4; ++g) {
      short8 vv = *(const short8*)(sp + g * 8);
#pragma unroll
      for (int e = 0; e < 8; ++e) acc[g * 8 + e] += bf2f((unsigned short)vv[e]);
    }
  }

  float inv = 1.f / lsum;
#pragma unroll
  for (int g = 0; g < 4; ++g) {
    short8 ov;
#pragma unroll
    for (int e = 0; e < 8; ++e) ov[e] = f2bf(acc[g * 8 + e] * inv);
    *(short8*)(aob + (size_t)(qt * 64 + row) * QKVS + h * 128 + cg + g * 8) = ov;
  }
}

// ---------------------------------------------------------------------------
// Workspace (bytes), peak 75,497,472 (< proven 79,691,776):
//   [0,        8388608)  xb  -> wo_b (after qkv gemm)
//   [8388608, 41943040)  wqkv -> {vtb@8388608, Opart@16777216, lpart@37748736}
//   [41943040,75497472)  qkv bf16 [2048][8192]; aob lives in v-cols (6144+)
// ---------------------------------------------------------------------------
extern "C" void kernel_launch(void* const* d_in, const int* in_sizes, int n_in,
                              void* d_out, int out_size, void* d_ws, size_t ws_size,
                              hipStream_t stream) {
  const float* x  = (const float*)d_in[0];
  const float* wq = (const float*)d_in[1];
  const float* wk = (const float*)d_in[2];
  const float* wv = (const float*)d_in[3];
  const float* wo = (const float*)d_in[4];
  const float* fc = (const float*)d_in[5];
  const float* fs = (const float*)d_in[6];

  char* ws8 = (char*)d_ws;
  short* xb    = (short*)(ws8 + 0);
  short* wo_b  = (short*)(ws8 + 0);
  short* wqkv  = (short*)(ws8 + 8388608);
  short* vtb   = (short*)(ws8 + 8388608);
  short* Opart = (short*)(ws8 + 16777216);
  float* lpart = (float*)(ws8 + 37748736);
  short* qkv   = (short*)(ws8 + 41943040);
  float* out   = (float*)d_out;

  const int NX4 = DIM * DIM / 4;
  const int NQKV4 = QKVS * DIM / 4;
  const int ROPE_GRID = (SEQ * NH * 32) / 256;

  bf16_convert<<<(NX4 + 255) / 256, 256, 0, stream>>>(x, xb, NX4);
  conv_wqkv<<<(NQKV4 + 255) / 256, 256, 0, stream>>>(wq, wk, wv, wqkv, NQKV4);

  // fused QKV projection: qkv [2048][8192]
  gemm_bt<true><<<dim3(QKVS / 128, SEQ / 128), 256, 0, stream>>>(
      xb, wqkv, qkv, DIM, DIM, DIM, QKVS, 1.0f);
  rope_qk<<<ROPE_GRID, 256, 0, stream>>>(qkv, fc, fs);
  vt_bf16<<<dim3(SEQ / 64, VD / 64), 256, 0, stream>>>(qkv + 2 * QKD, vtb);

  // wo convert (xb dead after qkv gemm)
  bf16_convert<<<(NX4 + 255) / 256, 256, 0, stream>>>(wo, wo_b, NX4);

  // split-T attention
  attn_part<<<dim3(SEQ / BQ, NH, 4), 256, 0, stream>>>(qkv, vtb, Opart, lpart);
  attn_combine<<<dim3(SEQ / BQ, NH), 256, 0, stream>>>(Opart, lpart, qkv + 2 * QKD);

  // output projection (A = aob in v-cols, lda = QKVS)
  gemm_bt<false><<<dim3(DIM / 128, SEQ / 128), 256, 0, stream>>>(
      qkv + 2 * QKD, wo_b, out, DIM, QKVS, DIM, DIM, 1.0f);
}

// Round 9
// 387.217 us; speedup vs baseline: 1.1791x; 1.0289x over previous
//
#include <hip/hip_runtime.h>
#include <hip/hip_bf16.h>
#include <math.h>

#define NH 16
#define NOPE 128
#define ROPE 64
#define VDIM 128
#define HD 192          // HEAD_DIM
#define SEQ 2048
#define DIM 2048
#define QKD (NH * HD)   // 3072
#define VD  (NH * VDIM) // 2048
#define QKVS 8192       // fused q|k|v row stride (shorts): [q 3072][k 3072][v 2048]

typedef __attribute__((ext_vector_type(8))) short short8;   // 8 bf16 = 4 VGPRs
typedef __attribute__((ext_vector_type(4))) short short4v;
typedef __attribute__((ext_vector_type(4))) float f32x4;
typedef unsigned int u32;

// s_waitcnt immediates (gfx9 encoding: vmcnt[3:0]@0, expcnt@4, lgkmcnt@8, vmcnt[5:4]@14)
#define WAIT_VM8  0x0F78   // vmcnt(8),  expcnt/lgkm no-wait
#define WAIT_VM0  0x0F70   // vmcnt(0)
#define WAIT_LGKM 0xC07F   // lgkmcnt(0), vmcnt/exp no-wait

static __device__ inline short f2bf(float f) {
  union { float f; unsigned u; } v; v.f = f;
  unsigned r = (v.u + 0x7fffu + ((v.u >> 16) & 1u)) >> 16;
  return (short)r;
}
static __device__ inline float bf2f(unsigned short u) {
  union { unsigned u; float f; } v; v.u = ((unsigned)u) << 16;
  return v.f;
}

// async global->LDS, 16B/lane. LDS dest = wave-uniform base + lane*16.
static __device__ __forceinline__ void gload16(const short* g, short* l) {
  __builtin_amdgcn_global_load_lds(
      (const __attribute__((address_space(1))) u32*)g,
      (__attribute__((address_space(3))) u32*)l, 16, 0, 0);
}

// ---------------------------------------------------------------------------
// bf16 MFMA GEMM v2: wave-private staging, NO barriers, fine-grained vmcnt.
// Each wave computes a 64x64 quadrant of the 128x128 block tile and stages
// its own A-half + B-half (double-buffered). XOR-swizzled LDS (2-way max).
// ---------------------------------------------------------------------------
template <bool BF16OUT>
__global__ __launch_bounds__(256) void gemm_bt(
    const short* __restrict__ A, const short* __restrict__ B,
    void* __restrict__ Cv, int K, int lda, int ldb, int ldc, float oscale) {
  // [wave][buf][ A 64x32 | B 64x32 ] = 4 * 2 * 4096 shorts = 64 KB
  __shared__ __align__(16) short Ls[4][2][4096];

  const int tid = threadIdx.x;
  const int lane = tid & 63;
  const int wave = tid >> 6;
  const int wr = wave >> 1, wc = wave & 1;
  const int lane15 = lane & 15, quad = lane >> 4;
  const int m0 = blockIdx.y * 128, n0 = blockIdx.x * 128;

  // staging addresses: chunk gidx = i*64+lane -> row gidx>>2, pos gidx&3,
  // global col = (pos ^ ((row>>1)&3)) * 8   (XOR swizzle, bank-period match)
  const short* gA[4]; const short* gB[4];
#pragma unroll
  for (int i = 0; i < 4; ++i) {
    int gidx = i * 64 + lane;
    int r = gidx >> 2, p = gidx & 3;
    int g = (p ^ ((r >> 1) & 3)) * 8;
    gA[i] = A + (size_t)(m0 + wr * 64 + r) * lda + g;
    gB[i] = B + (size_t)(n0 + wc * 64 + r) * ldb + g;
  }

  f32x4 acc[4][4];
#pragma unroll
  for (int i = 0; i < 4; ++i)
#pragma unroll
    for (int j = 0; j < 4; ++j) acc[i][j] = (f32x4)(0.f);

  // prologue: stage tile 0 into buf 0 (8 loads, wave-local)
#pragma unroll
  for (int i = 0; i < 4; ++i) gload16(gA[i], &Ls[wave][0][i * 512]);
#pragma unroll
  for (int i = 0; i < 4; ++i) gload16(gB[i], &Ls[wave][0][2048 + i * 512]);

  const int rsw = (lane15 >> 1) & 3;  // read-side swizzle
  for (int k0 = 0; k0 < K; k0 += 32) {
    const int cur = (k0 >> 5) & 1;
    // prior ds_reads complete before we overwrite their buffer (usually free)
    __builtin_amdgcn_s_waitcnt(WAIT_LGKM);
    if (k0 + 32 < K) {
      const int nxt = cur ^ 1;
#pragma unroll
      for (int i = 0; i < 4; ++i) gload16(gA[i] + k0 + 32, &Ls[wave][nxt][i * 512]);
#pragma unroll
      for (int i = 0; i < 4; ++i) gload16(gB[i] + k0 + 32, &Ls[wave][nxt][2048 + i * 512]);
      __builtin_amdgcn_s_waitcnt(WAIT_VM8);  // oldest 8 = tile cur landed
    } else {
      __builtin_amdgcn_s_waitcnt(WAIT_VM0);
    }
    const short* bufp = &Ls[wave][cur][0];
    short8 af[4], bfr[4];
#pragma unroll
    for (int i = 0; i < 4; ++i)
      af[i] = *(const short8*)&bufp[(i * 16 + lane15) * 32 + (quad ^ rsw) * 8];
#pragma unroll
    for (int j = 0; j < 4; ++j)
      bfr[j] = *(const short8*)&bufp[2048 + (j * 16 + lane15) * 32 + (quad ^ rsw) * 8];
#pragma unroll
    for (int i = 0; i < 4; ++i)
#pragma unroll
      for (int j = 0; j < 4; ++j)
        acc[i][j] = __builtin_amdgcn_mfma_f32_16x16x32_bf16(af[i], bfr[j], acc[i][j], 0, 0, 0);
  }

#pragma unroll
  for (int i = 0; i < 4; ++i)
#pragma unroll
    for (int j = 0; j < 4; ++j)
#pragma unroll
      for (int r = 0; r < 4; ++r) {
        size_t idx = (size_t)(m0 + wr * 64 + i * 16 + quad * 4 + r) * ldc +
                     n0 + wc * 64 + j * 16 + lane15;
        if (BF16OUT)
          ((short*)Cv)[idx] = f2bf(acc[i][j][r] * oscale);
        else
          ((float*)Cv)[idx] = acc[i][j][r];
      }
}

// ---------------------------------------------------------------------------
// RoPE in-place on fused qkv bf16 [SEQ][QKVS]: q pair + k pair per thread.
// ---------------------------------------------------------------------------
__global__ __launch_bounds__(256) void rope_qk(
    short* __restrict__ qk, const float* __restrict__ cosf, const float* __restrict__ sinf) {
  int idx = blockIdx.x * blockDim.x + threadIdx.x;
  int j = idx & 31;
  int h = (idx >> 5) & (NH - 1);
  int s = idx >> 9;
  if (s >= SEQ) return;

  float c = cosf[s * 32 + j];
  float sn = sinf[s * 32 + j];
  size_t rowb = (size_t)s * QKVS + h * HD + NOPE + 2 * j;

  u32* pq = (u32*)(qk + rowb);
  u32 w = *pq;
  float a = bf2f((unsigned short)(w & 0xffff));
  float b = bf2f((unsigned short)(w >> 16));
  *pq = (u32)(unsigned short)f2bf(a * c - b * sn) |
        ((u32)(unsigned short)f2bf(a * sn + b * c) << 16);

  u32* pk = (u32*)(qk + rowb + QKD);
  w = *pk;
  a = bf2f((unsigned short)(w & 0xffff));
  b = bf2f((unsigned short)(w >> 16));
  *pk = (u32)(unsigned short)f2bf(a * c - b * sn) |
        ((u32)(unsigned short)f2bf(a * sn + b * c) << 16);
}

// ---------------------------------------------------------------------------
// Converts.
// ---------------------------------------------------------------------------
__global__ __launch_bounds__(256) void bf16_convert(
    const float* __restrict__ in, short* __restrict__ out, int n4) {
  int i = blockIdx.x * 256 + threadIdx.x;
  if (i >= n4) return;
  float4 f = ((const float4*)in)[i];
  short4v o;
  o.x = f2bf(f.x); o.y = f2bf(f.y); o.z = f2bf(f.z); o.w = f2bf(f.w);
  ((short4v*)out)[i] = o;
}

// wq|wk|wv -> wqkv bf16 [8192][2048]
__global__ __launch_bounds__(256) void conv_wqkv(
    const float* __restrict__ wq, const float* __restrict__ wk,
    const float* __restrict__ wv, short* __restrict__ wqkv, int n4) {
  int i = blockIdx.x * 256 + threadIdx.x;
  if (i >= n4) return;
  int row = i >> 9;  // 512 float4 per 2048-col row
  float4 f;
  if (row < QKD) f = ((const float4*)wq)[i];
  else if (row < 2 * QKD) f = ((const float4*)wk)[i - QKD * (DIM / 4)];
  else f = ((const float4*)wv)[i - 2 * QKD * (DIM / 4)];
  short4v o;
  o.x = f2bf(f.x); o.y = f2bf(f.y); o.z = f2bf(f.z); o.w = f2bf(f.w);
  ((short4v*)wqkv)[i] = o;
}

// ---------------------------------------------------------------------------
// v bf16 (cols 6144.. of qkv, stride QKVS) -> vtb bf16 [h][d][t] transpose.
// ---------------------------------------------------------------------------
__global__ __launch_bounds__(256) void vt_bf16(
    const short* __restrict__ vb, short* __restrict__ vtb) {
  __shared__ short tile[64][74];
  const int t0 = blockIdx.x * 64;
  const int c0 = blockIdx.y * 64;
  const int tid = threadIdx.x;
#pragma unroll
  for (int i = 0; i < 16; ++i) {
    int idx = i * 256 + tid;
    int r = idx >> 6, c = idx & 63;
    tile[r][c] = vb[(size_t)(t0 + r) * QKVS + c0 + c];
  }
  __syncthreads();
  const int h = c0 >> 7;
  const int dbase = c0 & 127;
#pragma unroll
  for (int i = 0; i < 16; ++i) {
    int idx = i * 256 + tid;
    int d = idx >> 6, t = idx & 63;
    vtb[(size_t)h * VDIM * SEQ + (size_t)(dbase + d) * SEQ + t0 + t] = tile[t][d];
  }
}

// ---------------------------------------------------------------------------
// Split-T flash attention (1x4 wave layout), fixed-max softmax. Unchanged R8.
// ---------------------------------------------------------------------------
#define BQ 64
#define BT 64
#define CHT 8
#define PSTR 76
#define MFIX 8.0f

__global__ __launch_bounds__(256) void attn_part(
    const short* __restrict__ qk,   // [SEQ][QKVS] bf16
    const short* __restrict__ vtb,  // [NH][VDIM][SEQ] bf16
    short* __restrict__ Opart,      // [1280][64][128] bf16
    float* __restrict__ lpart)      // [1280][64] fp32
{
  __shared__ __align__(16) short Ks[BT * 192];    // 24576 B
  __shared__ __align__(16) short Vt[VDIM * 64];   // 16384 B
  __shared__ __align__(16) short Ps[4 * 16 * PSTR];

  const int qt = blockIdx.x;
  const int h = blockIdx.y;
  const int chk = blockIdx.z;
  if (chk * CHT > qt) return;

  const int tid = threadIdx.x;
  const int wave = tid >> 6;
  const int lane = tid & 63;
  const int lane15 = lane & 15;
  const int quad = lane >> 4;
  const int bb = qt >> 3;
  const int slot = h * 80 + qt + 4 * bb * (bb - 1) + (qt - 8 * bb) * bb + chk;
  const int R0 = qt * BQ;
  const int kt_beg = chk * CHT;
  const int kt_end = min(kt_beg + CHT, qt + 1);
  const float scale = 0.072168784f;  // 1/sqrt(192)

  // Q A-frags
  const int qrow = R0 + wave * 16 + lane15;
  short8 qf[6];
  const short* qbase = qk + (size_t)qrow * QKVS + h * HD + quad * 8;
#pragma unroll
  for (int kc = 0; kc < 6; ++kc) qf[kc] = *(const short8*)(qbase + kc * 32);

  // staging descriptors (XOR-swizzled)
  const short* kb = qk + QKD;
  const short* gK[6]; short* lK[6];
#pragma unroll
  for (int i = 0; i < 6; ++i) {
    int id = i * 256 + tid;
    int row = id / 24, cX = id - row * 24;
    int ch = cX ^ (row & 7);
    lK[i] = &Ks[id * 8];
    gK[i] = kb + (size_t)row * QKVS + h * HD + ch * 8;
  }
  const short* gV[4]; short* lV[4];
#pragma unroll
  for (int i = 0; i < 4; ++i) {
    int id = i * 256 + tid;
    int row = id >> 3, cX = id & 7;
    int ch = cX ^ (row & 7);
    lV[i] = &Vt[id * 8];
    gV[i] = vtb + (size_t)h * VDIM * SEQ + (size_t)row * SEQ + ch * 8;
  }

  f32x4 oacc[8];
#pragma unroll
  for (int i = 0; i < 8; ++i) oacc[i] = (f32x4)(0.f);
  float lsum[4] = {0.f, 0.f, 0.f, 0.f};

  short* pw = &Ps[wave * 16 * PSTR];

  for (int kt = kt_beg; kt < kt_end; ++kt) {
    const int t0 = kt * BT;
    __syncthreads();
#pragma unroll
    for (int i = 0; i < 6; ++i) gload16(gK[i] + (size_t)t0 * QKVS, lK[i]);
#pragma unroll
    for (int i = 0; i < 4; ++i) gload16(gV[i] + t0, lV[i]);
    __syncthreads();

    // S = Q K^T
    f32x4 sacc[4];
#pragma unroll
    for (int c = 0; c < 4; ++c) {
      sacc[c] = (f32x4)(0.f);
      const int row = c * 16 + lane15;
#pragma unroll
      for (int kc = 0; kc < 6; ++kc) {
        int cX = (4 * kc + quad) ^ (lane15 & 7);
        short8 kf = *(const short8*)&Ks[row * 192 + cX * 8];
        sacc[c] = __builtin_amdgcn_mfma_f32_16x16x32_bf16(qf[kc], kf, sacc[c], 0, 0, 0);
      }
    }

    if (kt == qt) {  // diagonal tile mask
#pragma unroll
      for (int c = 0; c < 4; ++c)
#pragma unroll
        for (int r = 0; r < 4; ++r) {
          int tloc = c * 16 + lane15;
          int qloc = wave * 16 + quad * 4 + r;
          if (tloc > qloc) sacc[c][r] = -1e30f;
        }
    }

    // P = exp(S*scale - MFIX); partial row sums; stage P bf16
#pragma unroll
    for (int c = 0; c < 4; ++c)
#pragma unroll
      for (int r = 0; r < 4; ++r) {
        float p = __expf(sacc[c][r] * scale - MFIX);
        lsum[r] += p;
        pw[(quad * 4 + r) * PSTR + c * 16 + lane15] = f2bf(p);
      }

    short8 pf0 = *(const short8*)&pw[lane15 * PSTR + quad * 8];
    short8 pf1 = *(const short8*)&pw[lane15 * PSTR + 32 + quad * 8];
#pragma unroll
    for (int ch = 0; ch < 8; ++ch) {
      const int row = ch * 16 + lane15;
      int cX0 = quad ^ (lane15 & 7);
      int cX1 = (4 + quad) ^ (lane15 & 7);
      short8 vf0 = *(const short8*)&Vt[row * 64 + cX0 * 8];
      short8 vf1 = *(const short8*)&Vt[row * 64 + cX1 * 8];
      oacc[ch] = __builtin_amdgcn_mfma_f32_16x16x32_bf16(pf0, vf0, oacc[ch], 0, 0, 0);
      oacc[ch] = __builtin_amdgcn_mfma_f32_16x16x32_bf16(pf1, vf1, oacc[ch], 0, 0, 0);
    }
  }

  // epilogue: write unnormalized partials
  short* op = Opart + (size_t)slot * (64 * 128);
#pragma unroll
  for (int ch = 0; ch < 8; ++ch)
#pragma unroll
    for (int r = 0; r < 4; ++r)
      op[(wave * 16 + quad * 4 + r) * 128 + ch * 16 + lane15] = f2bf(oacc[ch][r]);

  float red[4];
#pragma unroll
  for (int r = 0; r < 4; ++r) {
    float s = lsum[r];
    s += __shfl_xor(s, 1, 64);
    s += __shfl_xor(s, 2, 64);
    s += __shfl_xor(s, 4, 64);
    s += __shfl_xor(s, 8, 64);
    red[r] = s;
  }
  if (lane15 == 0) {
#pragma unroll
    for (int r = 0; r < 4; ++r)
      lpart[(size_t)slot * 64 + wave * 16 + quad * 4 + r] = red[r];
  }
}

// ---------------------------------------------------------------------------
// Phase B: sum chunk partials, normalize, write aob (into v-cols of qkv).
// ---------------------------------------------------------------------------
__global__ __launch_bounds__(256) void attn_combine(
    const short* __restrict__ Opart, const float* __restrict__ lpart,
    short* __restrict__ aob) {   // aob = qkv + 6144, row stride QKVS
  const int qt = blockIdx.x, h = blockIdx.y;
  const int nact = (qt >> 3) + 1;
  const int bb = qt >> 3;
  const int base = h * 80 + qt + 4 * bb * (bb - 1) + (qt - 8 * bb) * bb;
  const int tid = threadIdx.x;
  const int row = tid >> 2;
  const int cg = (tid & 3) * 32;

  float acc[32];
#pragma unroll
  for (int e = 0; e < 32; ++e) acc[e] = 0.f;
  float lsum = 0.f;

  for (int c = 0; c < nact; ++c) {
    const short* sp = Opart + (size_t)(base + c) * (64 * 128) + row * 128 + cg;
    lsum += lpart[(size_t)(base + c) * 64 + row];
#pragma unroll
    for (int g = 0; g < 4; ++g) {
      short8 vv = *(const short8*)(sp + g * 8);
#pragma unroll
      for (int e = 0; e < 8; ++e) acc[g * 8 + e] += bf2f((unsigned short)vv[e]);
    }
  }

  float inv = 1.f / lsum;
#pragma unroll
  for (int g = 0; g < 4; ++g) {
    short8 ov;
#pragma unroll
    for (int e = 0; e < 8; ++e) ov[e] = f2bf(acc[g * 8 + e] * inv);
    *(short8*)(aob + (size_t)(qt * 64 + row) * QKVS + h * 128 + cg + g * 8) = ov;
  }
}

// ---------------------------------------------------------------------------
// Workspace (bytes), peak 75,497,472 (< proven 79,691,776):
//   [0,        8388608)  xb  -> wo_b (after qkv gemm)
//   [8388608, 41943040)  wqkv -> {vtb@8388608, Opart@16777216, lpart@37748736}
//   [41943040,75497472)  qkv bf16 [2048][8192]; aob lives in v-cols (6144+)
// ---------------------------------------------------------------------------
extern "C" void kernel_launch(void* const* d_in, const int* in_sizes, int n_in,
                              void* d_out, int out_size, void* d_ws, size_t ws_size,
                              hipStream_t stream) {
  const float* x  = (const float*)d_in[0];
  const float* wq = (const float*)d_in[1];
  const float* wk = (const float*)d_in[2];
  const float* wv = (const float*)d_in[3];
  const float* wo = (const float*)d_in[4];
  const float* fc = (const float*)d_in[5];
  const float* fs = (const float*)d_in[6];

  char* ws8 = (char*)d_ws;
  short* xb    = (short*)(ws8 + 0);
  short* wo_b  = (short*)(ws8 + 0);
  short* wqkv  = (short*)(ws8 + 8388608);
  short* vtb   = (short*)(ws8 + 8388608);
  short* Opart = (short*)(ws8 + 16777216);
  float* lpart = (float*)(ws8 + 37748736);
  short* qkv   = (short*)(ws8 + 41943040);
  float* out   = (float*)d_out;

  const int NX4 = DIM * DIM / 4;
  const int NQKV4 = QKVS * DIM / 4;
  const int ROPE_GRID = (SEQ * NH * 32) / 256;

  bf16_convert<<<(NX4 + 255) / 256, 256, 0, stream>>>(x, xb, NX4);
  conv_wqkv<<<(NQKV4 + 255) / 256, 256, 0, stream>>>(wq, wk, wv, wqkv, NQKV4);

  // fused QKV projection: qkv [2048][8192]
  gemm_bt<true><<<dim3(QKVS / 128, SEQ / 128), 256, 0, stream>>>(
      xb, wqkv, qkv, DIM, DIM, DIM, QKVS, 1.0f);
  rope_qk<<<ROPE_GRID, 256, 0, stream>>>(qkv, fc, fs);
  vt_bf16<<<dim3(SEQ / 64, VD / 64), 256, 0, stream>>>(qkv + 2 * QKD, vtb);

  // wo convert (xb dead after qkv gemm)
  bf16_convert<<<(NX4 + 255) / 256, 256, 0, stream>>>(wo, wo_b, NX4);

  // split-T attention
  attn_part<<<dim3(SEQ / BQ, NH, 4), 256, 0, stream>>>(qkv, vtb, Opart, lpart);
  attn_combine<<<dim3(SEQ / BQ, NH), 256, 0, stream>>>(Opart, lpart, qkv + 2 * QKD);

  // output projection (A = aob in v-cols, lda = QKVS)
  gemm_bt<false><<<dim3(DIM / 128, SEQ / 128), 256, 0, stream>>>(
      qkv + 2 * QKD, wo_b, out, DIM, QKVS, DIM, DIM, 1.0f);
}